// Round 8
// baseline (388.885 us; speedup 1.0000x reference)
//
#include <hip/hip_runtime.h>
#include <hip/hip_bf16.h>

#define BH   16
#define SEQ  2048
#define DH   64

typedef _Float16 f16;
typedef unsigned int u32;
using f32x4 = __attribute__((ext_vector_type(4))) float;
using f16x8 = __attribute__((ext_vector_type(8))) _Float16;
using f16x4 = __attribute__((ext_vector_type(4))) _Float16;

// ---------------- scratch map (first 4 KB "FH" of out_attn rows 0..2047) ----
// K   f16 [bh][k][d]: FH chunk (bh*2048+k)>>5, offset (k&31)*128 + d*2  (rows 0..1023)
// V^T f16 [bh][d][k]: FH of row 1024 + bh*64 + d, offset k*2           (rows 1024..2047)
// P' strips (f16) live in the SECOND half (bytes 4096..8191) of every row ->
// byte-disjoint from scratch. pass_b overwrites all rows last, so scratch
// never leaks into the validated output.

// ============================ prep ============================
// K -> f16 row-major; V -> f16 transposed [d][k]. Runs once, ~24 MB traffic.
__global__ __launch_bounds__(256)
void mha_prep(const float* __restrict__ key, const float* __restrict__ value,
              char* __restrict__ scr)
{
  const int tid = threadIdx.x;
  if (blockIdx.x < 512) {           // ---- K path: 512 blocks x 64 k-rows ----
    const int bh = blockIdx.x >> 5;
    const int k  = (blockIdx.x & 31) * 64 + (tid >> 2);
    const int ds = (tid & 3) * 16;
    const float* src = key + ((size_t)(bh * SEQ + k)) * DH + ds;
    f32x4 a0 = *(const f32x4*)(src);
    f32x4 a1 = *(const f32x4*)(src + 4);
    f32x4 a2 = *(const f32x4*)(src + 8);
    f32x4 a3 = *(const f32x4*)(src + 12);
    f16x8 h0, h1;
    #pragma unroll
    for (int e = 0; e < 4; ++e) {
      h0[e] = (f16)a0[e]; h0[4 + e] = (f16)a1[e];
      h1[e] = (f16)a2[e]; h1[4 + e] = (f16)a3[e];
    }
    char* dst = scr + ((size_t)((bh * SEQ + k) >> 5)) * 8192 + (k & 31) * 128 + ds * 2;
    *(f16x8*)dst        = h0;
    *(f16x8*)(dst + 16) = h1;
  } else {                          // ---- V^T path: 256 blocks x 128 k ----
    __shared__ f16 Vl[64][136];
    const int vb = blockIdx.x - 512;
    const int bh = vb >> 4;
    const int kc = (vb & 15) * 128;
    {
      const int kl = tid >> 1, dh = (tid & 1) * 32;
      const float* src = value + ((size_t)(bh * SEQ + kc + kl)) * DH + dh;
      f32x4 a[8];
      #pragma unroll
      for (int j = 0; j < 8; ++j) a[j] = *(const f32x4*)(src + j * 4);
      #pragma unroll
      for (int j = 0; j < 32; ++j) Vl[dh + j][kl] = (f16)a[j >> 2][j & 3];
    }
    __syncthreads();
    {
      const int d = tid >> 2, ks = (tid & 3) * 32;
      char* dst = scr + ((size_t)(1024 + bh * 64 + d)) * 8192 + (kc + ks) * 2;
      #pragma unroll
      for (int m = 0; m < 4; ++m)
        *(f16x8*)(dst + m * 16) = *(const f16x8*)&Vl[d][ks + m * 8];
    }
  }
}

// ============================ pass A ============================
// Wave-autonomous, no LDS / no barriers in the loop. Each wave: 16 q-rows x
// 1024-k half. Per 16-k step: K-frags (L2 scratch), mask int4 (HBM), swapped
// QK MFMA, exp -> strip store + PV via 16x16x16 MFMA (p-vector IS the frag).
__global__ __launch_bounds__(256, 2)
void mha_pass_a(const char* __restrict__ kscr, const char* __restrict__ vscr,
                const float* __restrict__ query, const int* __restrict__ mask,
                const float* __restrict__ qmask,
                float* __restrict__ out_res, f16* __restrict__ strip)
{
  __shared__ float comb[2][64][17];
  const int tid  = threadIdx.x;
  const int lane = tid & 63;
  const int w    = tid >> 6;
  const int lr   = lane & 15;
  const int g    = lane >> 4;

  // XCD swizzle: 1024 blocks -> 128/XCD -> 2 bh per XCD (K/V^T L2-resident)
  const int idx = ((blockIdx.x & 7) << 7) + (blockIdx.x >> 3);
  const int bh  = idx >> 6;
  const int q0  = (((idx & 63) << 1) + (w >> 1)) << 4;   // q-tile base
  const int h   = w & 1;                                 // k-half

  // ---- Q fragments (f32 -> f16 registers) ----
  f16x8 qf0, qf1;
  {
    const float* qrow = query + ((size_t)(bh * SEQ + q0 + lr)) * DH;
    f32x4 a0 = *(const f32x4*)(qrow + g * 8);
    f32x4 a1 = *(const f32x4*)(qrow + g * 8 + 4);
    f32x4 a2 = *(const f32x4*)(qrow + 32 + g * 8);
    f32x4 a3 = *(const f32x4*)(qrow + 32 + g * 8 + 4);
    #pragma unroll
    for (int e = 0; e < 4; ++e) {
      qf0[e] = (f16)a0[e]; qf0[4 + e] = (f16)a1[e];
      qf1[e] = (f16)a2[e]; qf1[4 + e] = (f16)a3[e];
    }
  }

  const int* mrow = mask + (size_t)bh * SEQ * SEQ + (size_t)(q0 + lr) * SEQ;
  f16* srow = strip + ((size_t)(bh * SEQ + q0 + lr)) * 4096 + 2048;
  const char* vrow = vscr + ((size_t)(1024 + bh * 64 + lr)) * 8192;

  f32x4 oacc[4];
  #pragma unroll
  for (int d = 0; d < 4; ++d) oacc[d] = (f32x4){0.f, 0.f, 0.f, 0.f};
  float lsum = 0.f;

  #pragma unroll 2
  for (int K0 = h * 1024; K0 < h * 1024 + 1024; K0 += 16) {
    // K fragment: A[row = k-local = lr][d], swapped QK -> D[kloc=g*4+i][q=lr]
    const char* ka = kscr + ((size_t)((bh << 11) + K0) >> 5) * 8192
                   + ((K0 & 31) + lr) * 128;
    f16x8 kf0 = *(const f16x8*)(ka + g * 16);
    f16x8 kf1 = *(const f16x8*)(ka + 64 + g * 16);
    f32x4 s = {0.f, 0.f, 0.f, 0.f};
    s = __builtin_amdgcn_mfma_f32_16x16x32_f16(kf0, qf0, s, 0, 0, 0);
    s = __builtin_amdgcn_mfma_f32_16x16x32_f16(kf1, qf1, s, 0, 0, 0);

    const int4 mm = *(const int4*)(mrow + K0 + g * 4);
    const float p0 = mm.x ? 0.f : __expf(s[0] * 0.125f);
    const float p1 = mm.y ? 0.f : __expf(s[1] * 0.125f);
    const float p2 = mm.z ? 0.f : __expf(s[2] * 0.125f);
    const float p3 = mm.w ? 0.f : __expf(s[3] * 0.125f);
    lsum += (p0 + p1) + (p2 + p3);
    f16x4 pk = { (f16)p0, (f16)p1, (f16)p2, (f16)p3 };

    // unnormalized P' -> strip (8B store, lane-local)
    *(f16x4*)&srow[K0 + g * 4] = pk;

    // PV: pk is exactly the 16x16x16 B-frag B[col=q=lr][k=g*4..+4];
    // A-frag = V^T[d = dblk*16+lr][k=g*4..+4] (8B from L2 scratch).
    #pragma unroll
    for (int dblk = 0; dblk < 4; ++dblk) {
      f16x4 vf = *(const f16x4*)(vrow + dblk * (16 * 8192) + (K0 + g * 4) * 2);
      oacc[dblk] = __builtin_amdgcn_mfma_f32_16x16x16f16(vf, pk, oacc[dblk], 0, 0, 0);
    }
  }

  // ---- row sums: lanes sharing lr hold partials of row q0+lr ----
  lsum += __shfl_xor(lsum, 16);
  lsum += __shfl_xor(lsum, 32);

  // ---- combine the two k-halves (only barrier in the kernel) ----
  const int pair = w >> 1;
  if (h == 1) {
    #pragma unroll
    for (int d = 0; d < 4; ++d)
      #pragma unroll
      for (int i = 0; i < 4; ++i) comb[pair][lane][d * 4 + i] = oacc[d][i];
    comb[pair][lane][16] = lsum;
  }
  __syncthreads();
  if (h == 0) {
    #pragma unroll
    for (int d = 0; d < 4; ++d)
      #pragma unroll
      for (int i = 0; i < 4; ++i) oacc[d][i] += comb[pair][lane][d * 4 + i];
    lsum += comb[pair][lane][16];

    const float rsc = qmask[bh * SEQ + q0 + lr] / fmaxf(lsum, 1e-37f);
    float* orow = out_res + ((size_t)(bh * SEQ + q0 + lr)) * DH;
    #pragma unroll
    for (int d = 0; d < 4; ++d) {
      // lane holds O[q=lr][dblk*16 + g*4 + i]
      f32x4 o = { oacc[d][0] * rsc, oacc[d][1] * rsc,
                  oacc[d][2] * rsc, oacc[d][3] * rsc };
      *(f32x4*)(orow + d * 16 + g * 4) = o;
    }
  }
}

// ============================ pass B ============================
// One wave per row: read 4KB f16 strip (SH), l = sum, write full 8KB f32 row
// scaled by qmask/l. Reduction orders loads before stores -> in-place safe.
// Overwrites the FH scratch rows harmlessly (scratch is dead by now).
__global__ __launch_bounds__(256)
void mha_pass_b(const float* __restrict__ qmask,
                float* __restrict__ out_attn)
{
  const int lane = threadIdx.x & 63;
  const int wv   = threadIdx.x >> 6;
  const int row  = blockIdx.x * 4 + wv;

  float* rowp = out_attn + (size_t)row * SEQ;
  const f16x8* src = (const f16x8*)((const f16*)rowp + 2048 + lane * 32);

  f16x8 v0 = src[0], v1 = src[1], v2 = src[2], v3 = src[3];

  float f[32];
  #pragma unroll
  for (int j = 0; j < 8; ++j) {
    f[j]      = (float)v0[j];
    f[8 + j]  = (float)v1[j];
    f[16 + j] = (float)v2[j];
    f[24 + j] = (float)v3[j];
  }
  float lsum = 0.f;
  #pragma unroll
  for (int j = 0; j < 32; ++j) lsum += f[j];
  #pragma unroll
  for (int off = 1; off < 64; off <<= 1) lsum += __shfl_xor(lsum, off);

  const float scale = qmask[row] / fmaxf(lsum, 1e-37f);

  float4* dst = (float4*)(rowp + lane * 32);
  #pragma unroll
  for (int m = 0; m < 8; ++m) {
    float4 o = { f[m * 4 + 0] * scale, f[m * 4 + 1] * scale,
                 f[m * 4 + 2] * scale, f[m * 4 + 3] * scale };
    dst[m] = o;
  }
}

extern "C" void kernel_launch(void* const* d_in, const int* in_sizes, int n_in,
                              void* d_out, int out_size, void* d_ws, size_t ws_size,
                              hipStream_t stream) {
  const float* key   = (const float*)d_in[0];
  const float* value = (const float*)d_in[1];
  const float* query = (const float*)d_in[2];
  const int*   mask  = (const int*)d_in[3];
  const float* qmask = (const float*)d_in[4];

  float* out_res  = (float*)d_out;                       // [16,2048,64]
  float* out_attn = out_res + (size_t)BH * SEQ * DH;     // [16,2048,2048]

  mha_prep<<<dim3(768), dim3(256), 0, stream>>>(key, value, (char*)out_attn);

  mha_pass_a<<<dim3(1024), dim3(256), 0, stream>>>(
      (const char*)out_attn, (const char*)out_attn, query, mask, qmask,
      out_res, (f16*)out_attn);

  mha_pass_b<<<dim3(BH * SEQ / 4), dim3(256), 0, stream>>>(qmask, out_attn);
}